// Round 3
// baseline (186.333 us; speedup 1.0000x reference)
//

#include <hip/hip_runtime.h>
#include <hip/hip_bf16.h>
#include <math.h>

// ArcFace forward: out = S * modified, where modified == logits except at
// (row, label): cos(arccos(t) + MARGIN) = t*cos(m) - sqrt(1-t^2)*sin(m).
//
// R5 post-mortem: sched_barrier(0) did NOT force the 8-deep load batch —
// VGPR dropped to 20 (< 32 needed for 8 live float4), dur unchanged 61.6 us
// at 2.49 TB/s. Source-level hints lose; the compiler re-pairs load/store.
// Little's law says demand is the limit: 6.3 TB/s needs ~25 KB reads in
// flight per CU; VALUBusy 1.2% / Occ 54% indicate ~1 load in flight per
// wave, few active waves. m13 proves the mixed R/W path itself does 6.29
// TB/s (a copy is the same 1:1 mix).
//
// R6 (rerun — R6 bench hit GPUAcquisitionTimeout, never executed):
// (1) inline-asm batch — 8x global_load_dwordx4 + s_waitcnt vmcnt(0) in
// ONE asm block, early-clobber outputs: compiler cannot collapse it; forces
// 48 VGPRs live (proof visible in VGPR_Count). (2) grid = 2048 blocks
// (8/CU, fully co-resident) grid-striding over the 3125 chunk-units instead
// of 3125 short-lived blocks (~20 ns/block churn).
// Predicted: VGPR ~48-56, scale_copy 61.6 -> ~32-38 us, total ~150-158 us.
// If VGPR ~48 but dur ~61: demand theory dead -> supply/path limit.

#define ARC_S      64.0f
#define COS_M      0.8775825618903728f   // cos(0.5)
#define SIN_M      0.4794255386042030f   // sin(0.5)

typedef float floatx4 __attribute__((ext_vector_type(4)));

__global__ __launch_bounds__(256) void scale_copy_kernel(
    const floatx4* __restrict__ in,
    floatx4*       __restrict__ out,
    int nUnits)                      // units of 2048 float4 (32 KB)
{
    const int t = threadIdx.x;
    for (int bu = blockIdx.x; bu < nUnits; bu += gridDim.x) {
        const size_t base = (size_t)bu * 2048u + (size_t)t;
        const floatx4* p = in + base;

        floatx4 v0, v1, v2, v3, v4, v5, v6, v7;
        // 8 independent 16B loads issued back-to-back, then one wait.
        // Early-clobber outputs so result regs can't alias address regs
        // (loads return asynchronously after later loads issue).
        asm volatile(
            "global_load_dwordx4 %0, %8, off\n\t"
            "global_load_dwordx4 %1, %9, off\n\t"
            "global_load_dwordx4 %2, %10, off\n\t"
            "global_load_dwordx4 %3, %11, off\n\t"
            "global_load_dwordx4 %4, %12, off\n\t"
            "global_load_dwordx4 %5, %13, off\n\t"
            "global_load_dwordx4 %6, %14, off\n\t"
            "global_load_dwordx4 %7, %15, off\n\t"
            "s_waitcnt vmcnt(0)"
            : "=&v"(v0), "=&v"(v1), "=&v"(v2), "=&v"(v3),
              "=&v"(v4), "=&v"(v5), "=&v"(v6), "=&v"(v7)
            : "v"(p),        "v"(p + 256),  "v"(p + 512),  "v"(p + 768),
              "v"(p + 1024), "v"(p + 1280), "v"(p + 1536), "v"(p + 1792));

        out[base         ] = v0 * ARC_S;
        out[base +  256u ] = v1 * ARC_S;
        out[base +  512u ] = v2 * ARC_S;
        out[base +  768u ] = v3 * ARC_S;
        out[base + 1024u ] = v4 * ARC_S;
        out[base + 1280u ] = v5 * ARC_S;
        out[base + 1536u ] = v6 * ARC_S;
        out[base + 1792u ] = v7 * ARC_S;
    }
}

// Handles (1) the 256 target-element fixups, (2) any flat tail not covered
// by full 2048-float4 units (empty for 256x100000).
__global__ __launch_bounds__(256) void fixup_kernel(
    const float* __restrict__ logits,
    const int*   __restrict__ labels,
    float*       __restrict__ out,
    int B, int C, size_t tailStart, size_t total)
{
    const int t = threadIdx.x;

    // target fixup: one thread per row
    if (t < B) {
        const int lbl = labels[t];
        if (lbl >= 0 && lbl < C) {
            const size_t idx = (size_t)t * (size_t)C + (size_t)lbl;
            const float x = logits[idx];
            const float s = sqrtf(fmaxf(0.0f, 1.0f - x * x));
            out[idx] = ARC_S * (x * COS_M - s * SIN_M);
        }
    }

    // scalar tail (generic-shape safety; no-op when total % 8192 == 0)
    for (size_t i = tailStart + t; i < total; i += 256)
        out[i] = ARC_S * logits[i];
}

extern "C" void kernel_launch(void* const* d_in, const int* in_sizes, int n_in,
                              void* d_out, int out_size, void* d_ws, size_t ws_size,
                              hipStream_t stream) {
    const float* logits = (const float*)d_in[0];
    const int*   labels = (const int*)d_in[1];
    float*       out    = (float*)d_out;

    const int B = in_sizes[1];                 // 256
    const int C = in_sizes[0] / B;             // 100000
    const size_t total  = (size_t)B * (size_t)C;       // 25.6e6 floats
    const size_t total4 = total / 4;                   // 6.4e6 float4s
    const int    nUnits = (int)(total4 / 2048);        // 3125 full units
    const size_t tailStart = (size_t)nUnits * 2048u * 4u;  // == total here

    const int nBlocks = nUnits < 2048 ? nUnits : 2048; // fully co-resident

    scale_copy_kernel<<<dim3(nBlocks), dim3(256), 0, stream>>>(
        (const floatx4*)logits, (floatx4*)out, nUnits);
    fixup_kernel<<<dim3(1), dim3(256), 0, stream>>>(
        logits, labels, out, B, C, tailStart, total);
}


// Round 4
// 183.375 us; speedup vs baseline: 1.0161x; 1.0161x over previous
//

#include <hip/hip_runtime.h>
#include <hip/hip_cooperative_groups.h>
#include <math.h>

namespace cg = cooperative_groups;

// ArcFace forward: out = S * modified, where modified == logits except at
// (row, label): cos(arccos(t) + MARGIN) = t*cos(m) - sqrt(1-t^2)*sin(m).
//
// R6 post-mortem: asm-forced 8-deep load batch + co-resident grid changed
// NOTHING (62 us, 2.47 TB/s) despite ~128 KB outstanding reads/CU (20x the
// Little's-law need). Demand theory dead per pre-commit. Three different
// structures -> identical 62 us: limiter is the memory path for a 1:1
// interleaved R/W mix. Write-only fill sustains 6.6 TB/s on the same chip;
// HBM bus is shared R+W, so bus-direction mixing is the prime suspect.
//
// R7: DEVICE-wide phase separation (per-wave separation can't help: 16
// unsync'd waves/CU re-mix at the bus). Cooperative launch, 768 blocks x
// 256 thr (3 blocks/CU, co-resident by __launch_bounds__(256,3)), each
// thread parks 32 float4 in regs (128 VGPRs, structurally un-collapsible
// across grid.sync), then the whole device flips to write phase.
// 96.3% of traffic phase-separated; 1.7% tail mixed; fixup unchanged.
// Predicted: kernel 62 -> ~35 us if theory right (total ~160); ~55-60 us
// if reads are intrinsically capped (-> probe read path next round).

#define ARC_S      64.0f
#define COS_M      0.8775825618903728f   // cos(0.5)
#define SIN_M      0.4794255386042030f   // sin(0.5)

typedef float floatx4 __attribute__((ext_vector_type(4)));

#define PHASE_NB   768          // 3 blocks/CU x 256 CUs
#define PHASE_NT   256
#define PER_THREAD 32           // 32 x float4 = 128 data VGPRs parked

__global__ __launch_bounds__(PHASE_NT, 3) void phased_copy_kernel(
    const floatx4* __restrict__ in,
    floatx4*       __restrict__ out,
    size_t total4)
{
    const size_t stride = (size_t)PHASE_NB * PHASE_NT;            // 196608
    const size_t gtid   = (size_t)blockIdx.x * PHASE_NT + threadIdx.x;

    // ---- phase 1: pure-read at the bus. All 32 values live across the
    // grid sync -> compiler cannot sink stores between loads.
    floatx4 v[PER_THREAD];
    #pragma unroll
    for (int k = 0; k < PER_THREAD; ++k)
        v[k] = in[gtid + (size_t)k * stride];

    cg::this_grid().sync();

    // ---- phase 2: pure-write at the bus.
    #pragma unroll
    for (int k = 0; k < PER_THREAD; ++k)
        out[gtid + (size_t)k * stride] = v[k] * ARC_S;

    // tail (1.7% of traffic, mixed R/W): [PER_THREAD*stride, total4)
    for (size_t i = (size_t)PER_THREAD * stride + gtid; i < total4; i += stride)
        out[i] = in[i] * ARC_S;
}

// Proven fallback (R6): used only if cooperative capacity is unavailable
// or the shape is too small for the phased kernel.
__global__ __launch_bounds__(256) void scale_copy_kernel(
    const floatx4* __restrict__ in,
    floatx4*       __restrict__ out,
    int nUnits)                      // units of 2048 float4 (32 KB)
{
    const int t = threadIdx.x;
    for (int bu = blockIdx.x; bu < nUnits; bu += gridDim.x) {
        const size_t base = (size_t)bu * 2048u + (size_t)t;
        floatx4 v[8];
        #pragma unroll
        for (int j = 0; j < 8; ++j)
            v[j] = in[base + j * 256];
        #pragma unroll
        for (int j = 0; j < 8; ++j)
            out[base + j * 256] = v[j] * ARC_S;
    }
}

__global__ __launch_bounds__(256) void tail_copy_kernel(
    const float* __restrict__ in, float* __restrict__ out,
    size_t start, size_t total)
{
    for (size_t i = start + threadIdx.x + (size_t)blockIdx.x * 256u;
         i < total; i += (size_t)gridDim.x * 256u)
        out[i] = ARC_S * in[i];
}

// (1) the B target-element fixups, (2) any scalar tail not covered above.
__global__ __launch_bounds__(256) void fixup_kernel(
    const float* __restrict__ logits,
    const int*   __restrict__ labels,
    float*       __restrict__ out,
    int B, int C, size_t tailStart, size_t total)
{
    const int t = threadIdx.x;

    if (t < B) {
        const int lbl = labels[t];
        if (lbl >= 0 && lbl < C) {
            const size_t idx = (size_t)t * (size_t)C + (size_t)lbl;
            const float x = logits[idx];
            const float s = sqrtf(fmaxf(0.0f, 1.0f - x * x));
            out[idx] = ARC_S * (x * COS_M - s * SIN_M);
        }
    }

    for (size_t i = tailStart + t; i < total; i += 256)
        out[i] = ARC_S * logits[i];
}

extern "C" void kernel_launch(void* const* d_in, const int* in_sizes, int n_in,
                              void* d_out, int out_size, void* d_ws, size_t ws_size,
                              hipStream_t stream) {
    const float* logits = (const float*)d_in[0];
    const int*   labels = (const int*)d_in[1];
    float*       out    = (float*)d_out;

    const int B = in_sizes[1];                 // 256
    const int C = in_sizes[0] / B;             // 100000
    const size_t total  = (size_t)B * (size_t)C;       // 25.6e6 floats
    const size_t total4 = total / 4;                   // 6.4e6 float4s
    const size_t vecTail = total4 * 4;                 // floats covered by vec paths

    // One-time cooperative-capacity check (host-side queries only; no
    // allocs/syncs -> graph-capture safe).
    static int coopOK = -1;
    if (coopOK < 0) {
        int dev = 0;
        hipGetDevice(&dev);
        hipDeviceProp_t prop;
        hipGetDeviceProperties(&prop, dev);
        int perCU = 0;
        hipOccupancyMaxActiveBlocksPerMultiprocessor(
            &perCU, (const void*)phased_copy_kernel, PHASE_NT, 0);
        coopOK = ((long long)perCU * prop.multiProcessorCount >= PHASE_NB &&
                  prop.cooperativeLaunch) ? 1 : 0;
    }

    const size_t phaseCover = (size_t)PHASE_NB * PHASE_NT * PER_THREAD; // 6,291,456 f4

    if (coopOK == 1 && total4 >= phaseCover) {
        void* args[] = { (void*)&logits, (void*)&out, (void*)&total4 };
        hipLaunchCooperativeKernel((const void*)phased_copy_kernel,
                                   dim3(PHASE_NB), dim3(PHASE_NT),
                                   args, 0, stream);
    } else {
        const int nUnits = (int)(total4 / 2048);
        if (nUnits > 0) {
            const int nBlocks = nUnits < 2048 ? nUnits : 2048;
            scale_copy_kernel<<<dim3(nBlocks), dim3(256), 0, stream>>>(
                (const floatx4*)logits, (floatx4*)out, nUnits);
        }
        const size_t unitTail = (size_t)(total4 / 2048) * 2048u;
        if (unitTail < total4)
            tail_copy_kernel<<<dim3(64), dim3(256), 0, stream>>>(
                logits, out, unitTail * 4u, vecTail);
    }

    fixup_kernel<<<dim3(1), dim3(256), 0, stream>>>(
        logits, labels, out, B, C, vecTail, total);
}
